// Round 1
// baseline (228.799 us; speedup 1.0000x reference)
//
#include <hip/hip_runtime.h>

typedef unsigned short U16;
typedef __bf16 bf16x8 __attribute__((ext_vector_type(8)));
typedef float f32x4 __attribute__((ext_vector_type(4)));

__device__ inline float b2f(U16 u) {
    union { unsigned int i; float f; } v;
    v.i = ((unsigned int)u) << 16;
    return v.f;
}
__device__ inline U16 f2b(float f) {
    union { float f; unsigned int u; } v;
    v.f = f;
    unsigned int r = (v.u + 0x7fffu + ((v.u >> 16) & 1u)) >> 16;
    return (U16)r;
}

// async global->LDS, 16B per lane (LDS dest = wave-uniform base + lane*16)
__device__ inline void gld16(const void* g, void* l) {
    __builtin_amdgcn_global_load_lds(
        (const __attribute__((address_space(1))) void*)g,
        (__attribute__((address_space(3))) void*)l, 16, 0, 0);
}

// ------- Transpose + fp32->bf16: out[c][r] = bf16(in[r][c]), R x C /32 ------
__global__ void transpose_f2b(const float* __restrict__ in, U16* __restrict__ out,
                              int R, int C) {
    __shared__ float tile[32][33];
    int c0 = blockIdx.x * 32, r0 = blockIdx.y * 32;
    int tx = threadIdx.x, ty = threadIdx.y; // 32 x 8
#pragma unroll
    for (int i = 0; i < 32; i += 8)
        tile[ty + i][tx] = in[(size_t)(r0 + ty + i) * C + c0 + tx];
    __syncthreads();
#pragma unroll
    for (int i = 0; i < 32; i += 8)
        out[(size_t)(c0 + ty + i) * R + r0 + tx] = f2b(tile[tx][ty + i]);
}

// ------- LayerNorm: fp32 in -> bf16 out, one block (256 thr) per 1024-row ---
__global__ __launch_bounds__(256) void ln_kernel(const float* __restrict__ x,
                                                 const float* __restrict__ gamma,
                                                 const float* __restrict__ beta,
                                                 U16* __restrict__ xn) {
    int row = blockIdx.x;
    int t = threadIdx.x;
    float4 raw = ((const float4*)(x + (size_t)row * 1024))[t];
    float v[4] = { raw.x, raw.y, raw.z, raw.w };
    float s = v[0] + v[1] + v[2] + v[3];
    float s2 = v[0] * v[0] + v[1] * v[1] + v[2] * v[2] + v[3] * v[3];
#pragma unroll
    for (int off = 32; off >= 1; off >>= 1) {
        s  += __shfl_xor(s,  off);
        s2 += __shfl_xor(s2, off);
    }
    __shared__ float red[8];
    if ((t & 63) == 0) { red[(t >> 6) * 2] = s; red[(t >> 6) * 2 + 1] = s2; }
    __syncthreads();
    float S  = red[0] + red[2] + red[4] + red[6];
    float S2 = red[1] + red[3] + red[5] + red[7];
    float mu = S * (1.0f / 1024.0f);
    float var = S2 * (1.0f / 1024.0f) - mu * mu;
    float rstd = rsqrtf(var + 1e-5f);
    float4 g4 = ((const float4*)gamma)[t];
    float4 b4 = ((const float4*)beta)[t];
    ushort4 o;
    o.x = f2b((v[0] - mu) * rstd * g4.x + b4.x);
    o.y = f2b((v[1] - mu) * rstd * g4.y + b4.y);
    o.z = f2b((v[2] - mu) * rstd * g4.z + b4.z);
    o.w = f2b((v[3] - mu) * rstd * g4.w + b4.w);
    ((ushort4*)(xn + (size_t)row * 1024))[t] = o;
}

// ------ GEMM: C[M,N] = A[M,K] * Bt[N,K]^T (+fp32 bias), OutT = U16 or float -
// m97 structure: 128x128 tile, BK=32, global_load_lds width=16 staging.
// If vT != nullptr: N-tiles with n0 >= 2048 (the V third of QKV) are written
// transposed to vT[(b*16+h)*64+d][token] instead of C.
template <typename OutT>
__global__ __launch_bounds__(256) void gemm_bt(const U16* __restrict__ A,
                                               const U16* __restrict__ Bt,
                                               const float* __restrict__ bias,
                                               OutT* __restrict__ C,
                                               U16* __restrict__ vT,
                                               int M, int N, int K) {
    __shared__ __align__(16) U16 As[128 * 32];
    __shared__ __align__(16) U16 Bs[128 * 32];
    const int m0 = blockIdx.y * 128, n0 = blockIdx.x * 128;
    const int t = threadIdx.x;
    const int wave = t >> 6, lane = t & 63, l15 = lane & 15, quad = lane >> 4;
    const int wm = (wave >> 1) * 64, wn = (wave & 1) * 64;

    f32x4 acc[4][4];
#pragma unroll
    for (int i = 0; i < 4; i++)
#pragma unroll
        for (int j = 0; j < 4; j++)
            acc[i][j] = (f32x4){0.f, 0.f, 0.f, 0.f};

    const int c0i = t, c1i = 256 + t;
    const int r0 = c0i >> 2, kq0 = c0i & 3;
    const int r1 = c1i >> 2, kq1 = c1i & 3;

    for (int k0 = 0; k0 < K; k0 += 32) {
        gld16(&A[(size_t)(m0 + r0) * K + k0 + kq0 * 8], &As[c0i * 8]);
        gld16(&Bt[(size_t)(n0 + r0) * K + k0 + kq0 * 8], &Bs[c0i * 8]);
        gld16(&A[(size_t)(m0 + r1) * K + k0 + kq1 * 8], &As[c1i * 8]);
        gld16(&Bt[(size_t)(n0 + r1) * K + k0 + kq1 * 8], &Bs[c1i * 8]);
        __syncthreads();
        bf16x8 af[4], bfr[4];
#pragma unroll
        for (int i = 0; i < 4; i++)
            af[i] = *(const bf16x8*)&As[(wm + i * 16 + l15) * 32 + quad * 8];
#pragma unroll
        for (int j = 0; j < 4; j++)
            bfr[j] = *(const bf16x8*)&Bs[(wn + j * 16 + l15) * 32 + quad * 8];
#pragma unroll
        for (int i = 0; i < 4; i++)
#pragma unroll
            for (int j = 0; j < 4; j++)
                acc[i][j] = __builtin_amdgcn_mfma_f32_16x16x32_bf16(
                    af[i], bfr[j], acc[i][j], 0, 0, 0);
        __syncthreads();
    }
    if (vT && n0 >= 2048) {
#pragma unroll
        for (int i = 0; i < 4; i++) {
#pragma unroll
            for (int j = 0; j < 4; j++) {
                int col = n0 + wn + j * 16 + l15 - 2048;
                int hh = col >> 6, dd = col & 63;
                int row0 = m0 + wm + i * 16 + quad * 4;
                int bb = row0 >> 11, nn = row0 & 2047;
                ushort4 st;
                st.x = f2b(acc[i][j][0]); st.y = f2b(acc[i][j][1]);
                st.z = f2b(acc[i][j][2]); st.w = f2b(acc[i][j][3]);
                *(ushort4*)&vT[((((size_t)bb * 16) + hh) * 64 + dd) * 2048 + nn] = st;
            }
        }
        return;
    }
#pragma unroll
    for (int i = 0; i < 4; i++) {
#pragma unroll
        for (int j = 0; j < 4; j++) {
            int col = n0 + wn + j * 16 + l15;
            float bv = bias ? bias[col] : 0.0f;
#pragma unroll
            for (int r = 0; r < 4; r++) {
                int row = m0 + wm + i * 16 + quad * 4 + r;
                float val = acc[i][j][r] + bv;
                if constexpr (sizeof(OutT) == 4)
                    C[(size_t)row * N + col] = val;
                else
                    C[(size_t)row * N + col] = f2b(val);
            }
        }
    }
}

// ---- MFMA flash attention: Bq=64 (rf=1: 16 q-rows/wave), Bc=64, static
// softmax, async dbuf, XOR-swizzled LDS (conflict fix, see r10 note below).
//
// Occupancy redesign vs previous version (Bq=128, 512 blocks = 2 blocks/CU,
// Occupancy 18.5%, MfmaUtil 19%): halving rows/wave doubles the grid to 1024
// blocks and shrinks LDS to 41 KB -> 3 blocks/CU = 12 waves/CU. Latency
// exposure (the ~45% of iter time that was neither MFMA nor VALU) is the
// target; LDS frag traffic per FLOP doubles but stays ~55% of LDS BW.
//
// XCD swizzle: dispatch is round-robin over 8 XCDs (p & 7). Map blocks so
// all 32 q-tiles of one (b,h) land on ONE XCD -> its 512 KB K/V slice is
// fetched into that XCD's L2 once (4 bh/XCD = 2 MB < 4 MB L2) instead of
// 8x across all XCDs (prev FETCH_SIZE 71.7 MB vs ~25 MB unique).
//
// LDS swizzle (unchanged): row stride is 128 B = 32 banks, so an unswizzled
// b128 frag read piles 16 lanes on one 4-bank group. Chunk (row r, slot j)
// FETCHES global oct g = j^(r&7); readers take oct o of row r from slot
// o^(r&7). Coalescing unchanged (same 128B segment, permuted within).
#define PSTR 72
__global__ __launch_bounds__(256) void attn_kernel(const U16* __restrict__ qkv,
                                                   const U16* __restrict__ vT,
                                                   U16* __restrict__ attn_out) {
    const int p = blockIdx.x;              // 0..1023
    const int slot = p >> 3;               // 0..127 within XCD
    const int bh = ((slot & 3) << 3) | (p & 7);  // bh & 7 == XCD id
    const int qt = slot >> 2;              // 0..31, 64 q-rows per block
    const int b = bh >> 4, h = bh & 15;
    const int t = threadIdx.x;
    const int wave = t >> 6, lane = t & 63, l15 = lane & 15, quad = lane >> 4;
    const float sc2 = 0.125f * 1.44269504089f;  // scale * log2(e)

    __shared__ __align__(16) U16 Kt[2][64 * 64];    // [key][d-swizzled]
    __shared__ __align__(16) U16 Vt[2][64 * 64];    // [d][key-swizzled]
    __shared__ __align__(16) U16 Pb[4][16 * PSTR];  // per-wave [q][key]

    const size_t base = (size_t)(b * 2048) * 3072;
    const U16* vTbh = vT + ((size_t)(b * 16 + h) * 64) * 2048;

    bf16x8 qf[2];
    {
        int qrow = qt * 64 + wave * 16 + l15;
        const U16* qp = qkv + base + (size_t)qrow * 3072 + h * 64;
        qf[0] = *(const bf16x8*)&qp[quad * 8];
        qf[1] = *(const bf16x8*)&qp[32 + quad * 8];
    }

    float l_i[4] = { 0.f, 0.f, 0.f, 0.f };
    f32x4 o[4];
#pragma unroll
    for (int f = 0; f < 4; f++) o[f] = (f32x4){0.f, 0.f, 0.f, 0.f};

    // staging: chunk c -> LDS offset c*16B; row=c>>3, slot=c&7,
    // fetched global oct = slot ^ (row&7)
    const int c0 = t, c1 = 256 + t;
    const int row0 = c0 >> 3, oct0 = (c0 & 7) ^ (row0 & 7);
    const int row1 = c1 >> 3, oct1 = (c1 & 7) ^ (row1 & 7);
    // reader slot offset (elements): oct o of row r lives at slot o^(r&7)
    const int s0 = (quad ^ (l15 & 7)) * 8;        // octs 0..3; octs 4..7 = s0^32

    // prefetch tile 0 into buf 0
    gld16(&qkv[base + (size_t)row0 * 3072 + 1024 + h * 64 + oct0 * 8], &Kt[0][c0 * 8]);
    gld16(&qkv[base + (size_t)row1 * 3072 + 1024 + h * 64 + oct1 * 8], &Kt[0][c1 * 8]);
    gld16(&vTbh[(size_t)row0 * 2048 + oct0 * 8], &Vt[0][c0 * 8]);
    gld16(&vTbh[(size_t)row1 * 2048 + oct1 * 8], &Vt[0][c1 * 8]);
    __syncthreads();

    for (int kt = 0; kt < 32; kt++) {
        // ---- async prefetch of tile kt+1 (wraps harmlessly at the end) ----
        {
            int nt = (kt + 1) & 31, nb = (kt + 1) & 1;
            gld16(&qkv[base + (size_t)(nt * 64 + row0) * 3072 + 1024 + h * 64 + oct0 * 8], &Kt[nb][c0 * 8]);
            gld16(&qkv[base + (size_t)(nt * 64 + row1) * 3072 + 1024 + h * 64 + oct1 * 8], &Kt[nb][c1 * 8]);
            gld16(&vTbh[(size_t)row0 * 2048 + nt * 64 + oct0 * 8], &Vt[nb][c0 * 8]);
            gld16(&vTbh[(size_t)row1 * 2048 + nt * 64 + oct1 * 8], &Vt[nb][c1 * 8]);
        }
        const U16* KtC = &Kt[kt & 1][0];
        const U16* VtC = &Vt[kt & 1][0];

        // ---- K frags, then V frags hoisted early (latency hides under
        //      QK^T MFMA + exp; all drained by the lgkmcnt(0) below) ----
        bf16x8 k0[4], k1[4];
#pragma unroll
        for (int c = 0; c < 4; c++) {
            k0[c] = *(const bf16x8*)&KtC[(c * 16 + l15) * 64 + s0];
            k1[c] = *(const bf16x8*)&KtC[(c * 16 + l15) * 64 + (s0 ^ 32)];
        }
        bf16x8 vf0[4], vf1[4];
#pragma unroll
        for (int f = 0; f < 4; f++) {
            vf0[f] = *(const bf16x8*)&VtC[(f * 16 + l15) * 64 + s0];
            vf1[f] = *(const bf16x8*)&VtC[(f * 16 + l15) * 64 + (s0 ^ 32)];
        }

        // ---- QK^T ----
        f32x4 s[4];
        __builtin_amdgcn_s_setprio(1);
#pragma unroll
        for (int c = 0; c < 4; c++) {
            f32x4 z = (f32x4){0.f, 0.f, 0.f, 0.f};
            z = __builtin_amdgcn_mfma_f32_16x16x32_bf16(qf[0], k0[c], z, 0, 0, 0);
            z = __builtin_amdgcn_mfma_f32_16x16x32_bf16(qf[1], k1[c], z, 0, 0, 0);
            s[c] = z;
        }
        __builtin_amdgcn_s_setprio(0);

        // ---- softmax (static, exp2) + P pack to LDS ----
        U16* pb = &Pb[wave][0];
#pragma unroll
        for (int r = 0; r < 4; r++) {
#pragma unroll
            for (int c = 0; c < 4; c++) {
                float pe = __builtin_amdgcn_exp2f(s[c][r] * sc2);
                l_i[r] += pe;
                union { float f; unsigned int u; } cv; cv.f = pe;
                pb[(quad * 4 + r) * PSTR + c * 16 + l15] = (U16)(cv.u >> 16);
            }
        }

        // wave-local: drain our ds_writes (and frag reads) before cross-lane read
        asm volatile("s_waitcnt lgkmcnt(0)" ::: "memory");

        bf16x8 pf0 = *(const bf16x8*)&pb[l15 * PSTR + quad * 8];
        bf16x8 pf1 = *(const bf16x8*)&pb[l15 * PSTR + 32 + quad * 8];
        __builtin_amdgcn_s_setprio(1);
#pragma unroll
        for (int f = 0; f < 4; f++) {
            o[f] = __builtin_amdgcn_mfma_f32_16x16x32_bf16(pf0, vf0[f], o[f], 0, 0, 0);
            o[f] = __builtin_amdgcn_mfma_f32_16x16x32_bf16(pf1, vf1[f], o[f], 0, 0, 0);
        }
        __builtin_amdgcn_s_setprio(0);
        // one barrier per iter: protects buf reuse AND makes prefetch visible
        __syncthreads();
    }

#pragma unroll
    for (int r = 0; r < 4; r++) {
        float l = l_i[r];
#pragma unroll
        for (int off = 8; off >= 1; off >>= 1)
            l += __shfl_xor(l, off, 16);
        l_i[r] = 1.0f / l;
    }
#pragma unroll
    for (int f = 0; f < 4; f++) {
#pragma unroll
        for (int r = 0; r < 4; r++) {
            int row = b * 2048 + qt * 64 + wave * 16 + quad * 4 + r;
            int col = h * 64 + f * 16 + l15;
            attn_out[(size_t)row * 1024 + col] = f2b(o[f][r] * l_i[r]);
        }
    }
}

extern "C" void kernel_launch(void* const* d_in, const int* in_sizes, int n_in,
                              void* d_out, int out_size, void* d_ws, size_t ws_size,
                              hipStream_t stream) {
    (void)in_sizes; (void)n_in; (void)out_size; (void)ws_size;
    const float* x    = (const float*)d_in[0];
    const float* g    = (const float*)d_in[1];
    const float* be   = (const float*)d_in[2];
    const float* Wqkv = (const float*)d_in[3];
    const float* Wout = (const float*)d_in[4];
    const float* bout = (const float*)d_in[5];
    float* out = (float*)d_out;   // reference output dtype is fp32
    char* ws = (char*)d_ws;

    U16* xn   = (U16*)(ws);                          // 8 MB, reused as aout
    U16* qkv  = (U16*)(ws + (size_t)(8u  << 20));    // 24 MB (V third unused)
    U16* WqT  = (U16*)(ws + (size_t)(32u << 20));    // 6 MB
    U16* WoT  = (U16*)(ws + (size_t)(38u << 20));    // 2 MB
    U16* vT   = (U16*)(ws + (size_t)(40u << 20));    // 8 MB: V transposed
    U16* aout = xn;  // xn dead after GEMM1

    transpose_f2b<<<dim3(3072 / 32, 1024 / 32), dim3(32, 8), 0, stream>>>(Wqkv, WqT, 1024, 3072);
    transpose_f2b<<<dim3(1024 / 32, 1024 / 32), dim3(32, 8), 0, stream>>>(Wout, WoT, 1024, 1024);
    ln_kernel<<<4096, 256, 0, stream>>>(x, g, be, xn);
    gemm_bt<U16><<<dim3(3072 / 128, 4096 / 128), 256, 0, stream>>>(xn, WqT, nullptr, qkv, vT, 4096, 3072, 1024);
    attn_kernel<<<dim3(1024), 256, 0, stream>>>(qkv, vT, aout);
    gemm_bt<float><<<dim3(1024 / 128, 4096 / 128), 256, 0, stream>>>(aout, WoT, bout, out, nullptr, 4096, 1024, 1024);
}

// Round 2
// 226.593 us; speedup vs baseline: 1.0097x; 1.0097x over previous
//
#include <hip/hip_runtime.h>

typedef unsigned short U16;
typedef __bf16 bf16x8 __attribute__((ext_vector_type(8)));
typedef float f32x4 __attribute__((ext_vector_type(4)));

__device__ inline float b2f(U16 u) {
    union { unsigned int i; float f; } v;
    v.i = ((unsigned int)u) << 16;
    return v.f;
}
__device__ inline U16 f2b(float f) {
    union { float f; unsigned int u; } v;
    v.f = f;
    unsigned int r = (v.u + 0x7fffu + ((v.u >> 16) & 1u)) >> 16;
    return (U16)r;
}

// async global->LDS, 16B per lane (LDS dest = wave-uniform base + lane*16)
__device__ inline void gld16(const void* g, void* l) {
    __builtin_amdgcn_global_load_lds(
        (const __attribute__((address_space(1))) void*)g,
        (__attribute__((address_space(3))) void*)l, 16, 0, 0);
}

// ------- Transpose + fp32->bf16: out[c][r] = bf16(in[r][c]), R x C /32 ------
__global__ void transpose_f2b(const float* __restrict__ in, U16* __restrict__ out,
                              int R, int C) {
    __shared__ float tile[32][33];
    int c0 = blockIdx.x * 32, r0 = blockIdx.y * 32;
    int tx = threadIdx.x, ty = threadIdx.y; // 32 x 8
#pragma unroll
    for (int i = 0; i < 32; i += 8)
        tile[ty + i][tx] = in[(size_t)(r0 + ty + i) * C + c0 + tx];
    __syncthreads();
#pragma unroll
    for (int i = 0; i < 32; i += 8)
        out[(size_t)(c0 + ty + i) * R + r0 + tx] = f2b(tile[tx][ty + i]);
}

// ------- LayerNorm: fp32 in -> bf16 out, one block (256 thr) per 1024-row ---
__global__ __launch_bounds__(256) void ln_kernel(const float* __restrict__ x,
                                                 const float* __restrict__ gamma,
                                                 const float* __restrict__ beta,
                                                 U16* __restrict__ xn) {
    int row = blockIdx.x;
    int t = threadIdx.x;
    float4 raw = ((const float4*)(x + (size_t)row * 1024))[t];
    float v[4] = { raw.x, raw.y, raw.z, raw.w };
    float s = v[0] + v[1] + v[2] + v[3];
    float s2 = v[0] * v[0] + v[1] * v[1] + v[2] * v[2] + v[3] * v[3];
#pragma unroll
    for (int off = 32; off >= 1; off >>= 1) {
        s  += __shfl_xor(s,  off);
        s2 += __shfl_xor(s2, off);
    }
    __shared__ float red[8];
    if ((t & 63) == 0) { red[(t >> 6) * 2] = s; red[(t >> 6) * 2 + 1] = s2; }
    __syncthreads();
    float S  = red[0] + red[2] + red[4] + red[6];
    float S2 = red[1] + red[3] + red[5] + red[7];
    float mu = S * (1.0f / 1024.0f);
    float var = S2 * (1.0f / 1024.0f) - mu * mu;
    float rstd = rsqrtf(var + 1e-5f);
    float4 g4 = ((const float4*)gamma)[t];
    float4 b4 = ((const float4*)beta)[t];
    ushort4 o;
    o.x = f2b((v[0] - mu) * rstd * g4.x + b4.x);
    o.y = f2b((v[1] - mu) * rstd * g4.y + b4.y);
    o.z = f2b((v[2] - mu) * rstd * g4.z + b4.z);
    o.w = f2b((v[3] - mu) * rstd * g4.w + b4.w);
    ((ushort4*)(xn + (size_t)row * 1024))[t] = o;
}

// ------ GEMM: C[M,N] = A[M,K] * Bt[N,K]^T (+fp32 bias), OutT = U16 or float -
// m97 structure: 128x128 tile, BK=32, global_load_lds width=16 staging.
// If vT != nullptr: N-tiles with n0 >= 2048 (the V third of QKV) are written
// transposed to vT[(b*16+h)*64+d][token] instead of C.
template <typename OutT>
__global__ __launch_bounds__(256) void gemm_bt(const U16* __restrict__ A,
                                               const U16* __restrict__ Bt,
                                               const float* __restrict__ bias,
                                               OutT* __restrict__ C,
                                               U16* __restrict__ vT,
                                               int M, int N, int K) {
    __shared__ __align__(16) U16 As[128 * 32];
    __shared__ __align__(16) U16 Bs[128 * 32];
    const int m0 = blockIdx.y * 128, n0 = blockIdx.x * 128;
    const int t = threadIdx.x;
    const int wave = t >> 6, lane = t & 63, l15 = lane & 15, quad = lane >> 4;
    const int wm = (wave >> 1) * 64, wn = (wave & 1) * 64;

    f32x4 acc[4][4];
#pragma unroll
    for (int i = 0; i < 4; i++)
#pragma unroll
        for (int j = 0; j < 4; j++)
            acc[i][j] = (f32x4){0.f, 0.f, 0.f, 0.f};

    const int c0i = t, c1i = 256 + t;
    const int r0 = c0i >> 2, kq0 = c0i & 3;
    const int r1 = c1i >> 2, kq1 = c1i & 3;

    for (int k0 = 0; k0 < K; k0 += 32) {
        gld16(&A[(size_t)(m0 + r0) * K + k0 + kq0 * 8], &As[c0i * 8]);
        gld16(&Bt[(size_t)(n0 + r0) * K + k0 + kq0 * 8], &Bs[c0i * 8]);
        gld16(&A[(size_t)(m0 + r1) * K + k0 + kq1 * 8], &As[c1i * 8]);
        gld16(&Bt[(size_t)(n0 + r1) * K + k0 + kq1 * 8], &Bs[c1i * 8]);
        __syncthreads();
        bf16x8 af[4], bfr[4];
#pragma unroll
        for (int i = 0; i < 4; i++)
            af[i] = *(const bf16x8*)&As[(wm + i * 16 + l15) * 32 + quad * 8];
#pragma unroll
        for (int j = 0; j < 4; j++)
            bfr[j] = *(const bf16x8*)&Bs[(wn + j * 16 + l15) * 32 + quad * 8];
#pragma unroll
        for (int i = 0; i < 4; i++)
#pragma unroll
            for (int j = 0; j < 4; j++)
                acc[i][j] = __builtin_amdgcn_mfma_f32_16x16x32_bf16(
                    af[i], bfr[j], acc[i][j], 0, 0, 0);
        __syncthreads();
    }
    if (vT && n0 >= 2048) {
#pragma unroll
        for (int i = 0; i < 4; i++) {
#pragma unroll
            for (int j = 0; j < 4; j++) {
                int col = n0 + wn + j * 16 + l15 - 2048;
                int hh = col >> 6, dd = col & 63;
                int row0 = m0 + wm + i * 16 + quad * 4;
                int bb = row0 >> 11, nn = row0 & 2047;
                ushort4 st;
                st.x = f2b(acc[i][j][0]); st.y = f2b(acc[i][j][1]);
                st.z = f2b(acc[i][j][2]); st.w = f2b(acc[i][j][3]);
                *(ushort4*)&vT[((((size_t)bb * 16) + hh) * 64 + dd) * 2048 + nn] = st;
            }
        }
        return;
    }
#pragma unroll
    for (int i = 0; i < 4; i++) {
#pragma unroll
        for (int j = 0; j < 4; j++) {
            int col = n0 + wn + j * 16 + l15;
            float bv = bias ? bias[col] : 0.0f;
#pragma unroll
            for (int r = 0; r < 4; r++) {
                int row = m0 + wm + i * 16 + quad * 4 + r;
                float val = acc[i][j][r] + bv;
                if constexpr (sizeof(OutT) == 4)
                    C[(size_t)row * N + col] = val;
                else
                    C[(size_t)row * N + col] = f2b(val);
            }
        }
    }
}

// ---- MFMA flash attention, split-K partial kernel.
//
// r1 post-mortem: Bq=64 (rf=1) doubled LDS frag bytes/FLOP (every wave reads
// the full K/V tile regardless of q-rows owned) -> LDS pipe became the wall
// (~75% busy), attn regressed 68.7 -> 88.4 us. Lesson: buy occupancy without
// raising LDS bytes/FLOP.
//
// This version: keep the PROVEN r0 inner loop (rf=2, Bq=128, 32 q-rows/wave)
// and split the KEY dim instead. Static softmax (no running max) makes
// split-K exactly mergeable: partial o and partial l just add. Each block
// owns 16 of the 32 k-tiles -> total staging + frag traffic per FLOP is
// IDENTICAL to r0, but the grid doubles to 1024 -> 3 blocks/CU (LDS 50 KB,
// 3x51200 = 150 KB <= 160 KB) = 12 waves/CU for latency hiding.
//
// XCD swizzle (kept from r1, proven: FETCH 71.7 -> 12.5 MB): all blocks of
// one (b,h) land on one XCD; 4 bh/XCD -> K/V slice 2 MB < 4 MB L2.
//
// Partials: po[half] = unnormalized O (fp32), pl[half] = row sums. po0 lives
// in d_out (dead until GEMM2 overwrites), po1+pl in ws. merge_kernel
// normalizes and emits bf16 aout.
//
// LDS swizzle (unchanged): row stride is 128 B = 32 banks; chunk (row r,
// slot j) FETCHES global oct g = j^(r&7); readers take oct o of row r from
// slot o^(r&7). Coalescing unchanged, values bit-identical.
#define PSTR 72
__global__ __launch_bounds__(256) void attn_kernel(const U16* __restrict__ qkv,
                                                   const U16* __restrict__ vT,
                                                   float* __restrict__ po0,
                                                   float* __restrict__ po1,
                                                   float* __restrict__ pl) {
    const int p = blockIdx.x;                    // 0..1023
    const int xcd = p & 7;
    const int slot = p >> 3;                     // 0..127 within XCD
    const int bh = ((slot & 3) << 3) | xcd;      // bh & 7 == XCD id
    const int r2 = slot >> 2;                    // 0..31
    const int qt = r2 & 15;                      // 16 q-tiles of 128 rows
    const int half = r2 >> 4;                    // key half: tiles [half*16, half*16+16)
    const int b = bh >> 4, h = bh & 15;
    const int t = threadIdx.x;
    const int wave = t >> 6, lane = t & 63, l15 = lane & 15, quad = lane >> 4;
    const float sc2 = 0.125f * 1.44269504089f;  // scale * log2(e)

    __shared__ __align__(16) U16 Kt[2][64 * 64];    // [key][d-swizzled]
    __shared__ __align__(16) U16 Vt[2][64 * 64];    // [d][key-swizzled]
    __shared__ __align__(16) U16 Pb[4][32 * PSTR];  // per-wave [q][key]

    const size_t base = (size_t)(b * 2048) * 3072;
    const U16* vTbh = vT + ((size_t)(b * 16 + h) * 64) * 2048;
    const int kbase = half * 16;                 // first k-tile of our half

    bf16x8 qf[2][2];
#pragma unroll
    for (int rf = 0; rf < 2; rf++) {
        int qrow = qt * 128 + wave * 32 + rf * 16 + l15;
        const U16* qp = qkv + base + (size_t)qrow * 3072 + h * 64;
        qf[rf][0] = *(const bf16x8*)&qp[quad * 8];
        qf[rf][1] = *(const bf16x8*)&qp[32 + quad * 8];
    }

    float l_i[2][4];
    f32x4 o[2][4];
#pragma unroll
    for (int rf = 0; rf < 2; rf++) {
#pragma unroll
        for (int r = 0; r < 4; r++) l_i[rf][r] = 0.0f;
#pragma unroll
        for (int f = 0; f < 4; f++) o[rf][f] = (f32x4){0.f, 0.f, 0.f, 0.f};
    }

    // staging: chunk c -> LDS offset c*16B; row=c>>3, slot=c&7,
    // fetched global oct = slot ^ (row&7)
    const int c0 = t, c1 = 256 + t;
    const int row0 = c0 >> 3, oct0 = (c0 & 7) ^ (row0 & 7);
    const int row1 = c1 >> 3, oct1 = (c1 & 7) ^ (row1 & 7);
    // reader slot offset (elements): oct o of row r lives at slot o^(r&7)
    const int s0 = (quad ^ (l15 & 7)) * 8;        // octs 0..3; octs 4..7 = s0^32

    // prefetch tile kbase into buf 0
    {
        int nt = kbase;
        gld16(&qkv[base + (size_t)(nt * 64 + row0) * 3072 + 1024 + h * 64 + oct0 * 8], &Kt[0][c0 * 8]);
        gld16(&qkv[base + (size_t)(nt * 64 + row1) * 3072 + 1024 + h * 64 + oct1 * 8], &Kt[0][c1 * 8]);
        gld16(&vTbh[(size_t)row0 * 2048 + nt * 64 + oct0 * 8], &Vt[0][c0 * 8]);
        gld16(&vTbh[(size_t)row1 * 2048 + nt * 64 + oct1 * 8], &Vt[0][c1 * 8]);
    }
    __syncthreads();

    for (int i = 0; i < 16; i++) {
        // ---- async prefetch of tile i+1 (wraps harmlessly at the end) ----
        {
            int nt = kbase + ((i + 1) & 15), nb = (i + 1) & 1;
            gld16(&qkv[base + (size_t)(nt * 64 + row0) * 3072 + 1024 + h * 64 + oct0 * 8], &Kt[nb][c0 * 8]);
            gld16(&qkv[base + (size_t)(nt * 64 + row1) * 3072 + 1024 + h * 64 + oct1 * 8], &Kt[nb][c1 * 8]);
            gld16(&vTbh[(size_t)row0 * 2048 + nt * 64 + oct0 * 8], &Vt[nb][c0 * 8]);
            gld16(&vTbh[(size_t)row1 * 2048 + nt * 64 + oct1 * 8], &Vt[nb][c1 * 8]);
        }
        const U16* KtC = &Kt[i & 1][0];
        const U16* VtC = &Vt[i & 1][0];

        // ---- K frags + V frags hoisted (latency hides under QK^T MFMA +
        //      exp; all drained by the lgkmcnt(0) fence below) ----
        bf16x8 k0[4], k1[4];
#pragma unroll
        for (int c = 0; c < 4; c++) {
            k0[c] = *(const bf16x8*)&KtC[(c * 16 + l15) * 64 + s0];
            k1[c] = *(const bf16x8*)&KtC[(c * 16 + l15) * 64 + (s0 ^ 32)];
        }
        bf16x8 vf0[4], vf1[4];
#pragma unroll
        for (int f = 0; f < 4; f++) {
            vf0[f] = *(const bf16x8*)&VtC[(f * 16 + l15) * 64 + s0];
            vf1[f] = *(const bf16x8*)&VtC[(f * 16 + l15) * 64 + (s0 ^ 32)];
        }

        // ---- QK^T ----
        f32x4 s[2][4];
        __builtin_amdgcn_s_setprio(1);
#pragma unroll
        for (int rf = 0; rf < 2; rf++) {
#pragma unroll
            for (int c = 0; c < 4; c++) {
                f32x4 z = (f32x4){0.f, 0.f, 0.f, 0.f};
                z = __builtin_amdgcn_mfma_f32_16x16x32_bf16(qf[rf][0], k0[c], z, 0, 0, 0);
                z = __builtin_amdgcn_mfma_f32_16x16x32_bf16(qf[rf][1], k1[c], z, 0, 0, 0);
                s[rf][c] = z;
            }
        }
        __builtin_amdgcn_s_setprio(0);

        // ---- softmax (static, exp2) + P pack to LDS ----
        U16* pb = &Pb[wave][0];
#pragma unroll
        for (int rf = 0; rf < 2; rf++) {
#pragma unroll
            for (int r = 0; r < 4; r++) {
#pragma unroll
                for (int c = 0; c < 4; c++) {
                    float pe = __builtin_amdgcn_exp2f(s[rf][c][r] * sc2);
                    l_i[rf][r] += pe;
                    union { float f; unsigned int u; } cv; cv.f = pe;
                    pb[(rf * 16 + quad * 4 + r) * PSTR + c * 16 + l15] = (U16)(cv.u >> 16);
                }
            }
        }

        // wave-local: drain our ds_writes (and frag reads) before cross-lane read
        asm volatile("s_waitcnt lgkmcnt(0)" ::: "memory");

        __builtin_amdgcn_s_setprio(1);
#pragma unroll
        for (int rf = 0; rf < 2; rf++) {
            bf16x8 pf0 = *(const bf16x8*)&pb[(rf * 16 + l15) * PSTR + quad * 8];
            bf16x8 pf1 = *(const bf16x8*)&pb[(rf * 16 + l15) * PSTR + 32 + quad * 8];
#pragma unroll
            for (int f = 0; f < 4; f++) {
                o[rf][f] = __builtin_amdgcn_mfma_f32_16x16x32_bf16(pf0, vf0[f], o[rf][f], 0, 0, 0);
                o[rf][f] = __builtin_amdgcn_mfma_f32_16x16x32_bf16(pf1, vf1[f], o[rf][f], 0, 0, 0);
            }
        }
        __builtin_amdgcn_s_setprio(0);
        // one barrier per iter: protects buf reuse AND makes prefetch visible
        __syncthreads();
    }

    // ---- partial epilogue: unnormalized o + row-sum l ----
#pragma unroll
    for (int rf = 0; rf < 2; rf++) {
#pragma unroll
        for (int r = 0; r < 4; r++) {
            float l = l_i[rf][r];
#pragma unroll
            for (int off = 8; off >= 1; off >>= 1)
                l += __shfl_xor(l, off, 16);
            l_i[rf][r] = l;
        }
    }
    float* po_h = half ? po1 : po0;
#pragma unroll
    for (int rf = 0; rf < 2; rf++) {
#pragma unroll
        for (int f = 0; f < 4; f++) {
#pragma unroll
            for (int r = 0; r < 4; r++) {
                int row = b * 2048 + qt * 128 + wave * 32 + rf * 16 + quad * 4 + r;
                int col = h * 64 + f * 16 + l15;
                po_h[(size_t)row * 1024 + col] = o[rf][f][r];
            }
        }
        if (l15 == 0) {
#pragma unroll
            for (int r = 0; r < 4; r++) {
                int row = b * 2048 + qt * 128 + wave * 32 + rf * 16 + quad * 4 + r;
                pl[((size_t)half * 4096 + row) * 16 + h] = l_i[rf][r];
            }
        }
    }
}

// ---- merge: aout = bf16((po0 + po1) / (l0 + l1)), one block per row ----
__global__ __launch_bounds__(256) void merge_kernel(const float* __restrict__ po0,
                                                    const float* __restrict__ po1,
                                                    const float* __restrict__ pl,
                                                    U16* __restrict__ aout) {
    int row = blockIdx.x;
    int t = threadIdx.x;
    int h = t >> 4;                              // cols 4t..4t+3 all in head h
    float inv = 1.0f / (pl[(size_t)row * 16 + h] + pl[((size_t)4096 + row) * 16 + h]);
    float4 a = ((const float4*)(po0 + (size_t)row * 1024))[t];
    float4 c = ((const float4*)(po1 + (size_t)row * 1024))[t];
    ushort4 o;
    o.x = f2b((a.x + c.x) * inv);
    o.y = f2b((a.y + c.y) * inv);
    o.z = f2b((a.z + c.z) * inv);
    o.w = f2b((a.w + c.w) * inv);
    ((ushort4*)(aout + (size_t)row * 1024))[t] = o;
}

extern "C" void kernel_launch(void* const* d_in, const int* in_sizes, int n_in,
                              void* d_out, int out_size, void* d_ws, size_t ws_size,
                              hipStream_t stream) {
    (void)in_sizes; (void)n_in; (void)out_size; (void)ws_size;
    const float* x    = (const float*)d_in[0];
    const float* g    = (const float*)d_in[1];
    const float* be   = (const float*)d_in[2];
    const float* Wqkv = (const float*)d_in[3];
    const float* Wout = (const float*)d_in[4];
    const float* bout = (const float*)d_in[5];
    float* out = (float*)d_out;   // reference output dtype is fp32
    char* ws = (char*)d_ws;

    U16* xn   = (U16*)(ws);                          // 8 MB, reused as aout
    U16* qkv  = (U16*)(ws + (size_t)(8u  << 20));    // 24 MB (V third unused)
    U16* WqT  = (U16*)(ws + (size_t)(32u << 20));    // 6 MB
    U16* WoT  = (U16*)(ws + (size_t)(38u << 20));    // 2 MB
    U16* vT   = (U16*)(ws + (size_t)(40u << 20));    // 8 MB: V transposed
    float* po1 = (float*)(ws + (size_t)(48u << 20)); // 16 MB: split-K half-1 O
    float* pl  = (float*)(ws + (size_t)(64u << 20)); // 512 KB: row sums [2][4096][16]
    U16* aout = xn;  // xn dead after GEMM1; written by merge
    float* po0 = out;  // d_out as scratch: dead until GEMM2 overwrites it

    transpose_f2b<<<dim3(3072 / 32, 1024 / 32), dim3(32, 8), 0, stream>>>(Wqkv, WqT, 1024, 3072);
    transpose_f2b<<<dim3(1024 / 32, 1024 / 32), dim3(32, 8), 0, stream>>>(Wout, WoT, 1024, 1024);
    ln_kernel<<<4096, 256, 0, stream>>>(x, g, be, xn);
    gemm_bt<U16><<<dim3(3072 / 128, 4096 / 128), 256, 0, stream>>>(xn, WqT, nullptr, qkv, vT, 4096, 3072, 1024);
    attn_kernel<<<dim3(1024), 256, 0, stream>>>(qkv, vT, po0, po1, pl);
    merge_kernel<<<dim3(4096), 256, 0, stream>>>(po0, po1, pl, aout);
    gemm_bt<float><<<dim3(1024 / 128, 4096 / 128), 256, 0, stream>>>(aout, WoT, bout, out, nullptr, 4096, 1024, 1024);
}

// Round 3
// 207.817 us; speedup vs baseline: 1.1010x; 1.0904x over previous
//
#include <hip/hip_runtime.h>

typedef unsigned short U16;
typedef __bf16 bf16x8 __attribute__((ext_vector_type(8)));
typedef float f32x4 __attribute__((ext_vector_type(4)));
typedef float f32x16 __attribute__((ext_vector_type(16)));

__device__ inline float b2f(U16 u) {
    union { unsigned int i; float f; } v;
    v.i = ((unsigned int)u) << 16;
    return v.f;
}
__device__ inline U16 f2b(float f) {
    union { float f; unsigned int u; } v;
    v.f = f;
    unsigned int r = (v.u + 0x7fffu + ((v.u >> 16) & 1u)) >> 16;
    return (U16)r;
}

// pack two f32 -> two bf16 in one u32 (RNE, same as f2b)
__device__ inline unsigned cvt_pk(float lo, float hi) {
    unsigned d;
    asm("v_cvt_pk_bf16_f32 %0, %1, %2" : "=v"(d) : "v"(lo), "v"(hi));
    return d;
}
// swap: a[lanes 32-63] <-> b[lanes 0-31]
__device__ inline void plswap(unsigned &a, unsigned &b) {
    asm("v_permlane32_swap_b32 %0, %1" : "+v"(a), "+v"(b));
}

// async global->LDS, 16B per lane (LDS dest = wave-uniform base + lane*16)
__device__ inline void gld16(const void* g, void* l) {
    __builtin_amdgcn_global_load_lds(
        (const __attribute__((address_space(1))) void*)g,
        (__attribute__((address_space(3))) void*)l, 16, 0, 0);
}

// ------- Transpose + fp32->bf16: out[c][r] = bf16(in[r][c]), R x C /32 ------
__global__ void transpose_f2b(const float* __restrict__ in, U16* __restrict__ out,
                              int R, int C) {
    __shared__ float tile[32][33];
    int c0 = blockIdx.x * 32, r0 = blockIdx.y * 32;
    int tx = threadIdx.x, ty = threadIdx.y; // 32 x 8
#pragma unroll
    for (int i = 0; i < 32; i += 8)
        tile[ty + i][tx] = in[(size_t)(r0 + ty + i) * C + c0 + tx];
    __syncthreads();
#pragma unroll
    for (int i = 0; i < 32; i += 8)
        out[(size_t)(c0 + ty + i) * R + r0 + tx] = f2b(tile[tx][ty + i]);
}

// ------- LayerNorm: fp32 in -> bf16 out, one block (256 thr) per 1024-row ---
__global__ __launch_bounds__(256) void ln_kernel(const float* __restrict__ x,
                                                 const float* __restrict__ gamma,
                                                 const float* __restrict__ beta,
                                                 U16* __restrict__ xn) {
    int row = blockIdx.x;
    int t = threadIdx.x;
    float4 raw = ((const float4*)(x + (size_t)row * 1024))[t];
    float v[4] = { raw.x, raw.y, raw.z, raw.w };
    float s = v[0] + v[1] + v[2] + v[3];
    float s2 = v[0] * v[0] + v[1] * v[1] + v[2] * v[2] + v[3] * v[3];
#pragma unroll
    for (int off = 32; off >= 1; off >>= 1) {
        s  += __shfl_xor(s,  off);
        s2 += __shfl_xor(s2, off);
    }
    __shared__ float red[8];
    if ((t & 63) == 0) { red[(t >> 6) * 2] = s; red[(t >> 6) * 2 + 1] = s2; }
    __syncthreads();
    float S  = red[0] + red[2] + red[4] + red[6];
    float S2 = red[1] + red[3] + red[5] + red[7];
    float mu = S * (1.0f / 1024.0f);
    float var = S2 * (1.0f / 1024.0f) - mu * mu;
    float rstd = rsqrtf(var + 1e-5f);
    float4 g4 = ((const float4*)gamma)[t];
    float4 b4 = ((const float4*)beta)[t];
    ushort4 o;
    o.x = f2b((v[0] - mu) * rstd * g4.x + b4.x);
    o.y = f2b((v[1] - mu) * rstd * g4.y + b4.y);
    o.z = f2b((v[2] - mu) * rstd * g4.z + b4.z);
    o.w = f2b((v[3] - mu) * rstd * g4.w + b4.w);
    ((ushort4*)(xn + (size_t)row * 1024))[t] = o;
}

// ------ GEMM: C[M,N] = A[M,K] * Bt[N,K]^T (+fp32 bias), OutT = U16 or float -
// m97 structure: 128x128 tile, BK=32, global_load_lds width=16 staging.
// If vT != nullptr: N-tiles with n0 >= 2048 (the V third of QKV) are written
// transposed to vT[(b*16+h)*64+d][token] instead of C.
template <typename OutT>
__global__ __launch_bounds__(256) void gemm_bt(const U16* __restrict__ A,
                                               const U16* __restrict__ Bt,
                                               const float* __restrict__ bias,
                                               OutT* __restrict__ C,
                                               U16* __restrict__ vT,
                                               int M, int N, int K) {
    __shared__ __align__(16) U16 As[128 * 32];
    __shared__ __align__(16) U16 Bs[128 * 32];
    const int m0 = blockIdx.y * 128, n0 = blockIdx.x * 128;
    const int t = threadIdx.x;
    const int wave = t >> 6, lane = t & 63, l15 = lane & 15, quad = lane >> 4;
    const int wm = (wave >> 1) * 64, wn = (wave & 1) * 64;

    f32x4 acc[4][4];
#pragma unroll
    for (int i = 0; i < 4; i++)
#pragma unroll
        for (int j = 0; j < 4; j++)
            acc[i][j] = (f32x4){0.f, 0.f, 0.f, 0.f};

    const int c0i = t, c1i = 256 + t;
    const int r0 = c0i >> 2, kq0 = c0i & 3;
    const int r1 = c1i >> 2, kq1 = c1i & 3;

    for (int k0 = 0; k0 < K; k0 += 32) {
        gld16(&A[(size_t)(m0 + r0) * K + k0 + kq0 * 8], &As[c0i * 8]);
        gld16(&Bt[(size_t)(n0 + r0) * K + k0 + kq0 * 8], &Bs[c0i * 8]);
        gld16(&A[(size_t)(m0 + r1) * K + k0 + kq1 * 8], &As[c1i * 8]);
        gld16(&Bt[(size_t)(n0 + r1) * K + k0 + kq1 * 8], &Bs[c1i * 8]);
        __syncthreads();
        bf16x8 af[4], bfr[4];
#pragma unroll
        for (int i = 0; i < 4; i++)
            af[i] = *(const bf16x8*)&As[(wm + i * 16 + l15) * 32 + quad * 8];
#pragma unroll
        for (int j = 0; j < 4; j++)
            bfr[j] = *(const bf16x8*)&Bs[(wn + j * 16 + l15) * 32 + quad * 8];
#pragma unroll
        for (int i = 0; i < 4; i++)
#pragma unroll
            for (int j = 0; j < 4; j++)
                acc[i][j] = __builtin_amdgcn_mfma_f32_16x16x32_bf16(
                    af[i], bfr[j], acc[i][j], 0, 0, 0);
        __syncthreads();
    }
    if (vT && n0 >= 2048) {
#pragma unroll
        for (int i = 0; i < 4; i++) {
#pragma unroll
            for (int j = 0; j < 4; j++) {
                int col = n0 + wn + j * 16 + l15 - 2048;
                int hh = col >> 6, dd = col & 63;
                int row0 = m0 + wm + i * 16 + quad * 4;
                int bb = row0 >> 11, nn = row0 & 2047;
                ushort4 st;
                st.x = f2b(acc[i][j][0]); st.y = f2b(acc[i][j][1]);
                st.z = f2b(acc[i][j][2]); st.w = f2b(acc[i][j][3]);
                *(ushort4*)&vT[((((size_t)bb * 16) + hh) * 64 + dd) * 2048 + nn] = st;
            }
        }
        return;
    }
#pragma unroll
    for (int i = 0; i < 4; i++) {
#pragma unroll
        for (int j = 0; j < 4; j++) {
            int col = n0 + wn + j * 16 + l15;
            float bv = bias ? bias[col] : 0.0f;
#pragma unroll
            for (int r = 0; r < 4; r++) {
                int row = m0 + wm + i * 16 + quad * 4 + r;
                float val = acc[i][j][r] + bv;
                if constexpr (sizeof(OutT) == 4)
                    C[(size_t)row * N + col] = val;
                else
                    C[(size_t)row * N + col] = f2b(val);
            }
        }
    }
}

// ---- MFMA flash attention, in-register-softmax version.
//
// r0-r2 post-mortem: the kernel is LDS-throughput-bound (~70% LDS-unit busy:
// 64 KB K/V/P frag reads + 16 KB staging per block-iter ~= 1850 cyc; MfmaUtil
// pinned at 16-19% across occupancy/split-K variants because the LDS data
// path is per-CU shared). Fix = cut LDS bytes/FLOP, not occupancy.
//
// Structure (m214/HK-style, 32x32x16 MFMA):
//  * 4 waves x 32 q-rows (Bq=128), KVBLK=64, 32 k-tiles, async dbuf staging
//    (unchanged), XCD swizzle (proven: FETCH 71.7 -> 14 MB).
//  * Swapped QK^T: S^T = mfma(K_frag, Q_frag). C/D layout (m74/m101): col =
//    lane&31 = q, row = (reg&3)+8*(reg>>2)+4*(lane>>5) = key. Each lane holds
//    ONE q-column -> softmax row-sum is lane-local (1 scalar, merged once at
//    the end via shfl_xor 32). P never touches LDS.
//  * P -> bf16 PV B-operand in registers: v_cvt_pk_bf16_f32 pairs +
//    v_permlane32_swap_b32 (hi/lo half exchange) assemble B[k][q] frags.
//  * PV: O^T = mfma(V^T_frag, P^T_frag); V^T frags = b128 reads from the
//    existing vT [d][key] LDS layout. O register-resident.
//  LDS/block-iter: 16 b128/wave x 4 waves + 16 KB DMA ~= 900 cyc (was 1850);
//  no mid-loop lgkmcnt fence, no Pb buffer (LDS 50 -> 32 KB).
//
// LDS oct swizzle (unchanged): row stride 128 B = 32 banks; chunk (row r,
// slot j) FETCHES global oct g = j^(r&7); readers take oct o of row r from
// slot o^(r&7). Coalescing unchanged, values bit-identical.
__global__ __launch_bounds__(256) void attn_kernel(const U16* __restrict__ qkv,
                                                   const U16* __restrict__ vT,
                                                   U16* __restrict__ attn_out) {
    const int p = blockIdx.x;                    // 0..511
    const int xcd = p & 7;
    const int slot = p >> 3;                     // 0..63 within XCD
    const int bh = ((slot & 3) << 3) | xcd;      // bh & 7 == XCD id
    const int qt = slot >> 2;                    // 0..15, 128 q-rows per block
    const int b = bh >> 4, h = bh & 15;
    const int t = threadIdx.x;
    const int wave = t >> 6, lane = t & 63;
    const int l31 = lane & 31, hi = lane >> 5;
    const float sc2 = 0.125f * 1.44269504089f;  // scale * log2(e)

    __shared__ __align__(16) U16 Kt[2][64 * 64];    // [key][d-swizzled]
    __shared__ __align__(16) U16 Vt[2][64 * 64];    // [d][key-swizzled]

    const size_t base = (size_t)(b * 2048) * 3072;
    const U16* vTbh = vT + ((size_t)(b * 16 + h) * 64) * 2048;

    // Q fragments (B-operand of swapped QK^T): lane(hi,q=l31) holds
    // Q[qrow][d = s*16 + hi*8 .. +8] for k-slices s=0..3
    bf16x8 qf[4];
    {
        int qrow = qt * 128 + wave * 32 + l31;
        const U16* qp = qkv + base + (size_t)qrow * 3072 + h * 64 + hi * 8;
#pragma unroll
        for (int s = 0; s < 4; s++)
            qf[s] = *(const bf16x8*)&qp[s * 16];
    }

    float l_acc = 0.0f;
    f32x16 oacc[2];  // O^T[d][q]: db*32 + (reg&3)+8*(reg>>2)+4*hi, col q=l31
#pragma unroll
    for (int db = 0; db < 2; db++)
#pragma unroll
        for (int r = 0; r < 16; r++)
            oacc[db][r] = 0.0f;

    // staging: chunk c -> LDS offset c*16B; row=c>>3, slot=c&7,
    // fetched global oct = slot ^ (row&7)
    const int c0 = t, c1 = 256 + t;
    const int row0 = c0 >> 3, oct0 = (c0 & 7) ^ (row0 & 7);
    const int row1 = c1 >> 3, oct1 = (c1 & 7) ^ (row1 & 7);

    // prefetch tile 0 into buf 0
    gld16(&qkv[base + (size_t)row0 * 3072 + 1024 + h * 64 + oct0 * 8], &Kt[0][c0 * 8]);
    gld16(&qkv[base + (size_t)row1 * 3072 + 1024 + h * 64 + oct1 * 8], &Kt[0][c1 * 8]);
    gld16(&vTbh[(size_t)row0 * 2048 + oct0 * 8], &Vt[0][c0 * 8]);
    gld16(&vTbh[(size_t)row1 * 2048 + oct1 * 8], &Vt[0][c1 * 8]);
    __syncthreads();

    for (int kt = 0; kt < 32; kt++) {
        // ---- async prefetch of tile kt+1 (wraps harmlessly at the end) ----
        {
            int nt = (kt + 1) & 31, nb = (kt + 1) & 1;
            gld16(&qkv[base + (size_t)(nt * 64 + row0) * 3072 + 1024 + h * 64 + oct0 * 8], &Kt[nb][c0 * 8]);
            gld16(&qkv[base + (size_t)(nt * 64 + row1) * 3072 + 1024 + h * 64 + oct1 * 8], &Kt[nb][c1 * 8]);
            gld16(&vTbh[(size_t)row0 * 2048 + nt * 64 + oct0 * 8], &Vt[nb][c0 * 8]);
            gld16(&vTbh[(size_t)row1 * 2048 + nt * 64 + oct1 * 8], &Vt[nb][c1 * 8]);
        }
        const U16* KtC = &Kt[kt & 1][0];
        const U16* VtC = &Vt[kt & 1][0];

#pragma unroll
        for (int kb = 0; kb < 2; kb++) {
            // ---- K A-frags: K[key = kb*32+l31][d = s*16 + hi*8 ..+8] ----
            bf16x8 kf[4];
#pragma unroll
            for (int s = 0; s < 4; s++)
                kf[s] = *(const bf16x8*)&KtC[(kb * 32 + l31) * 64 +
                                             (((s * 2 + hi) ^ (l31 & 7)) * 8)];
            // ---- V A-frags issued early (latency under QK^T + softmax):
            //      V^T[d = db*32+l31][key = kb*32 + s*16 + hi*8 ..+8] ----
            bf16x8 vfr[2][2];
#pragma unroll
            for (int db = 0; db < 2; db++)
#pragma unroll
                for (int s = 0; s < 2; s++)
                    vfr[db][s] = *(const bf16x8*)&VtC[(db * 32 + l31) * 64 +
                                                      (((kb * 4 + s * 2 + hi) ^ (l31 & 7)) * 8)];

            // ---- QK^T: S^T[key][q] ----
            f32x16 st = {0.f, 0.f, 0.f, 0.f, 0.f, 0.f, 0.f, 0.f,
                         0.f, 0.f, 0.f, 0.f, 0.f, 0.f, 0.f, 0.f};
            __builtin_amdgcn_s_setprio(1);
#pragma unroll
            for (int s = 0; s < 4; s++)
                st = __builtin_amdgcn_mfma_f32_32x32x16_bf16(kf[s], qf[s], st, 0, 0, 0);
            __builtin_amdgcn_s_setprio(0);

            // ---- softmax (static, exp2), lane-local row sum ----
            float pe[16];
#pragma unroll
            for (int r = 0; r < 16; r++) {
                pe[r] = __builtin_amdgcn_exp2f(st[r] * sc2);
                l_acc += pe[r];
            }

            // ---- pack P^T into PV B-frags (registers only) ----
            // regs s*8 + {0..7} = keys kb*32 + s*16 + {4hi+0..3, 8+4hi+0..3};
            // after 2 swaps per slice, word e holds keys (hi*8+2e, hi*8+2e+1).
#pragma unroll
            for (int s = 0; s < 2; s++) {
                unsigned p01 = cvt_pk(pe[s * 8 + 0], pe[s * 8 + 1]);
                unsigned p23 = cvt_pk(pe[s * 8 + 2], pe[s * 8 + 3]);
                unsigned p45 = cvt_pk(pe[s * 8 + 4], pe[s * 8 + 5]);
                unsigned p67 = cvt_pk(pe[s * 8 + 6], pe[s * 8 + 7]);
                plswap(p01, p45);
                plswap(p23, p67);
                union { unsigned u[4]; bf16x8 v; } pw;
                pw.u[0] = p01; pw.u[1] = p23; pw.u[2] = p45; pw.u[3] = p67;
                // ---- PV: O^T += V^T x P^T ----
                __builtin_amdgcn_s_setprio(1);
#pragma unroll
                for (int db = 0; db < 2; db++)
                    oacc[db] = __builtin_amdgcn_mfma_f32_32x32x16_bf16(
                        vfr[db][s], pw.v, oacc[db], 0, 0, 0);
                __builtin_amdgcn_s_setprio(0);
            }
        }
        // one barrier per iter: protects buf reuse AND makes prefetch visible
        __syncthreads();
    }

    // ---- epilogue: merge hi/lo half sums, normalize, store ----
    float lt = l_acc + __shfl_xor(l_acc, 32);
    float inv = 1.0f / lt;
    int qrow = b * 2048 + qt * 128 + wave * 32 + l31;
#pragma unroll
    for (int db = 0; db < 2; db++) {
#pragma unroll
        for (int g = 0; g < 4; g++) {
            ushort4 stv;
            stv.x = f2b(oacc[db][g * 4 + 0] * inv);
            stv.y = f2b(oacc[db][g * 4 + 1] * inv);
            stv.z = f2b(oacc[db][g * 4 + 2] * inv);
            stv.w = f2b(oacc[db][g * 4 + 3] * inv);
            int col = h * 64 + db * 32 + g * 8 + hi * 4;
            *(ushort4*)&attn_out[(size_t)qrow * 1024 + col] = stv;
        }
    }
}

extern "C" void kernel_launch(void* const* d_in, const int* in_sizes, int n_in,
                              void* d_out, int out_size, void* d_ws, size_t ws_size,
                              hipStream_t stream) {
    (void)in_sizes; (void)n_in; (void)out_size; (void)ws_size;
    const float* x    = (const float*)d_in[0];
    const float* g    = (const float*)d_in[1];
    const float* be   = (const float*)d_in[2];
    const float* Wqkv = (const float*)d_in[3];
    const float* Wout = (const float*)d_in[4];
    const float* bout = (const float*)d_in[5];
    float* out = (float*)d_out;   // reference output dtype is fp32
    char* ws = (char*)d_ws;

    U16* xn   = (U16*)(ws);                          // 8 MB, reused as aout
    U16* qkv  = (U16*)(ws + (size_t)(8u  << 20));    // 24 MB (V third unused)
    U16* WqT  = (U16*)(ws + (size_t)(32u << 20));    // 6 MB
    U16* WoT  = (U16*)(ws + (size_t)(38u << 20));    // 2 MB
    U16* vT   = (U16*)(ws + (size_t)(40u << 20));    // 8 MB: V transposed
    U16* aout = xn;  // xn dead after GEMM1

    transpose_f2b<<<dim3(3072 / 32, 1024 / 32), dim3(32, 8), 0, stream>>>(Wqkv, WqT, 1024, 3072);
    transpose_f2b<<<dim3(1024 / 32, 1024 / 32), dim3(32, 8), 0, stream>>>(Wout, WoT, 1024, 1024);
    ln_kernel<<<4096, 256, 0, stream>>>(x, g, be, xn);
    gemm_bt<U16><<<dim3(3072 / 128, 4096 / 128), 256, 0, stream>>>(xn, WqT, nullptr, qkv, vT, 4096, 3072, 1024);
    attn_kernel<<<dim3(512), 256, 0, stream>>>(qkv, vT, aout);
    gemm_bt<float><<<dim3(1024 / 128, 4096 / 128), 256, 0, stream>>>(aout, WoT, bout, out, nullptr, 4096, 1024, 1024);
}